// Round 4
// baseline (9.716 us; speedup 1.0000x reference)
//
#include <hip/hip_runtime.h>
#include <math.h>

// Problem: psi' = expm(-i*dt_b*kron(a a^T, I2)) @ expm(-i*zeta*kron(a+a^T, sigma_x)) @ psi
//   N = 64 Fock levels, full space 2N = 128, B = 1024 states.
// Math:
//   kick: X = a + a^T tridiagonal (couplings sqrt(i+1)). In sigma_x eigenbasis
//     u+/- = s0 +/- s1:  u+/- <- exp(-/+ i*zeta*X) u+/-.  3-step splitting,
//     order-20 Taylor Horner (theta/step <= 2*sqrt(63)/3 = 5.29, remainder ~4e-5/step);
//     tridiag matvec via DPP wave_shl/shr (lane = Fock idx).
//     Per-iteration couplings cp_k=(h/k)*sqrt(i+1), cm_k=(h/k)*sqrt(i) precomputed
//     into registers -> inner loop is 4 DPP + 4 FMA (neg via free src modifier).
//   rot: kron(a@a^T, I2) is DIAGONAL = diag(1..63,0) per spin -> phase exp(-i*dt*d).
// Wave decomposition: 2048 waves; wave pair per state (parity 0 -> u+, 1 -> u-),
//   2 waves/SIMD. Output: harness compares Re(psi) only ([B,128] floats);
//   dispatch on out_size.

#define FOCK_N 64
#define BATCH_B 1024
#define M_STEPS 3
#define P_ORDER 20

// DPP neighbor exchange (wave_shl:1 / wave_shr:1, zero-fill at edge).
__device__ __forceinline__ float dpp_nxt(float x) {  // out[i] = x[i+1], lane63 -> 0
    return __int_as_float(__builtin_amdgcn_update_dpp(
        0, __float_as_int(x), 0x130, 0xF, 0xF, true));   // wave_shl:1
}
__device__ __forceinline__ float dpp_prv(float x) {  // out[i] = x[i-1], lane0 -> 0
    return __int_as_float(__builtin_amdgcn_update_dpp(
        0, __float_as_int(x), 0x138, 0xF, 0xF, true));   // wave_shr:1
}

template <bool REAL_ONLY>
__global__ __launch_bounds__(256) void gate_kernel(
    const float* __restrict__ X,         // [B]
    const float* __restrict__ state_re,  // [B, 128]
    const float* __restrict__ state_im,  // [B, 128]
    const float* __restrict__ a_re,      // [64, 64]
    const float* __restrict__ zeta_p,    // [1]
    const float* __restrict__ time_p,    // [1]
    float* __restrict__ out)
{
    const int lane = threadIdx.x & 63;
    const int wv   = threadIdx.x >> 6;   // 0..3
    const int wst  = wv >> 1;            // state within block (0,1)
    const int par  = wv & 1;             // 0: u+ chain, 1: u- chain
    const int b    = blockIdx.x * 2 + wst;

    const float zeta = zeta_p[0];
    const float dt   = X[b] + time_p[0];

    // tridiagonal couplings: (X w)[i] = sqp*w[i+1] + sqm*w[i-1]
    const float sqp = (lane < FOCK_N - 1) ? a_re[lane * FOCK_N + lane + 1] : 0.0f;
    const float sqm = (lane > 0)          ? a_re[(lane - 1) * FOCK_N + lane] : 0.0f;

    // state element (Fock=lane, spin=t) at flat b*128 + 2*lane + t
    const float2 sre = ((const float2*)state_re)[b * FOCK_N + lane];
    const float2 sim = ((const float2*)state_im)[b * FOCK_N + lane];

    const float sgn = par ? -1.0f : 1.0f;     // u = s0 + sgn*s1; exp(-sgn*i*zeta*X)
    float ur = sre.x + sgn * sre.y;
    float ui = sim.x + sgn * sim.y;

    const float hh = sgn * (zeta / (float)M_STEPS);  // signed step

    // Precompute per-iteration fused couplings: cp[j]=(hh/k)*sqp, cm[j]=(hh/k)*sqm,
    // k = P_ORDER - j (Horner descending). 40 VGPRs, reused across all 3 steps.
    float cp[P_ORDER], cm[P_ORDER];
    #pragma unroll
    for (int j = 0; j < P_ORDER; ++j) {
        const int k = P_ORDER - j;
        const float c = hh * (1.0f / (float)k);   // compile-time 1/k
        cp[j] = c * sqp;
        cm[j] = c * sqm;
    }

    for (int step = 0; step < M_STEPS; ++step) {
        float wr = ur, wi = ui;
        #pragma unroll
        for (int j = 0; j < P_ORDER; ++j) {
            // w <- u + (hh/k)*(-i)*(X w):
            //   wr' = ur + c*(X wi) = fma(cm, wi_p, fma(cp, wi_n, ur))
            //   wi' = ui - c*(X wr) = fma(-cm, wr_p, fma(-cp, wr_n, ui))
            const float wi_n = dpp_nxt(wi), wi_p = dpp_prv(wi);
            const float wr_n = dpp_nxt(wr), wr_p = dpp_prv(wr);
            const float wrn = __builtin_fmaf(cm[j], wi_p,
                              __builtin_fmaf(cp[j], wi_n, ur));
            const float win = __builtin_fmaf(-cm[j], wr_p,
                              __builtin_fmaf(-cp[j], wr_n, ui));
            wr = wrn; wi = win;
        }
        ur = wr; ui = wi;
    }

    // recombine u+ / u- across the wave pair
    __shared__ float2 ex[2][2][FOCK_N];   // [state][parity][lane] = (ur, ui)
    ex[wst][par][lane] = make_float2(ur, ui);
    __syncthreads();

    if (par == 0) {
        const float2 um = ex[wst][1][lane];       // u-
        const float s0r = 0.5f * (ur + um.x), s0i = 0.5f * (ui + um.y);
        const float s1r = 0.5f * (ur - um.x), s1i = 0.5f * (ui - um.y);

        // rotation: phase exp(-i*dt*d), d = lane+1 (lane<63), 0 (lane==63)
        const float d = (lane < FOCK_N - 1) ? (float)(lane + 1) : 0.0f;
        float sn, cn;
        sincosf(dt * d, &sn, &cn);
        const float r0r = cn * s0r + sn * s0i;
        const float r0i = cn * s0i - sn * s0r;
        const float r1r = cn * s1r + sn * s1i;
        const float r1i = cn * s1i - sn * s1r;

        if (REAL_ONLY) {
            // expected = Re(psi): out[b*128 + 2*lane + s]
            ((float2*)out)[b * FOCK_N + lane] = make_float2(r0r, r1r);
        } else {
            ((float4*)out)[b * FOCK_N + lane] = make_float4(r0r, r0i, r1r, r1i);
        }
    }
}

extern "C" void kernel_launch(void* const* d_in, const int* in_sizes, int n_in,
                              void* d_out, int out_size, void* d_ws, size_t ws_size,
                              hipStream_t stream) {
    const float* X        = (const float*)d_in[0];
    const float* state_re = (const float*)d_in[1];
    const float* state_im = (const float*)d_in[2];
    const float* a_re     = (const float*)d_in[3];
    const float* zeta_p   = (const float*)d_in[4];
    const float* time_p   = (const float*)d_in[5];
    float* out = (float*)d_out;

    dim3 grid(BATCH_B / 2);   // wave pair per state, 2 states per 256-thread block
    dim3 block(256);
    if (out_size <= BATCH_B * 2 * FOCK_N) {
        gate_kernel<true><<<grid, block, 0, stream>>>(X, state_re, state_im, a_re,
                                                      zeta_p, time_p, out);
    } else {
        gate_kernel<false><<<grid, block, 0, stream>>>(X, state_re, state_im, a_re,
                                                       zeta_p, time_p, out);
    }
}